// Round 2
// baseline (172.886 us; speedup 1.0000x reference)
//
#include <hip/hip_runtime.h>
#include <math.h>

// Problem constants (from reference)
#define EMBED 1024
#define FFN_DIM 4096
#define TOKENS (8 * 2048)
#define EPS 1e-5f

typedef __attribute__((ext_vector_type(4))) float f32x4;

__device__ __forceinline__ void circuit_cvec(const float* p, float cv[4]) {
    float c0 = cosf(p[0]);
    float c1 = cosf(p[1]);
    float c2 = cosf(p[2]);
    float c3 = cosf(p[3]);
    cv[0] = c1 * c2 * c3;
    cv[1] = c0 * c1;
    cv[2] = c0 * c1 * c2;
    cv[3] = c0 * c1 * c2 * c3;
}

// --- Kernel A: h[f] = relu(sum_k w2[f,k] * cvec_f[k]),  f in [0, 4096) ---
__global__ __launch_bounds__(256) void k_hidden(const float* __restrict__ w2,
                                                const float* __restrict__ ffn_p,
                                                float* __restrict__ h) {
    int f = blockIdx.x * 256 + threadIdx.x;
    float cv[4];
    circuit_cvec(ffn_p, cv);
    f32x4 row = *(const f32x4*)(w2 + f * 4);
    float s = row.x * cv[0] + row.y * cv[1] + row.z * cv[2] + row.w * cv[3];
    h[f] = s > 0.f ? s : 0.f;
}

// --- Kernel B: one wave per output element e in [0,1024):
//   attn_out[e] = sum_j cvec[j&3] * w_mix[e, j]   (j in [0,1024))
//   ffn_out[e]  = sum_f h[f]      * w_out[e, f]   (f in [0,4096))
__global__ __launch_bounds__(256) void k_const(const float* __restrict__ w_mix,
                                               const float* __restrict__ attn_p,
                                               const float* __restrict__ w_out,
                                               const float* __restrict__ h,
                                               float* __restrict__ attn_out,
                                               float* __restrict__ ffn_out) {
    int e = blockIdx.x * 4 + (threadIdx.x >> 6);  // wave id = output element
    int lane = threadIdx.x & 63;
    float cv[4];
    circuit_cvec(attn_p, cv);

    // attn dot: 16 fp32 per lane, contiguous, 4x 16B loads
    float sa = 0.f;
    const float* wm = w_mix + e * EMBED + lane * 16;
    #pragma unroll
    for (int c = 0; c < 4; ++c) {
        f32x4 u = *(const f32x4*)(wm + c * 4);
        sa += u.x * cv[0] + u.y * cv[1] + u.z * cv[2] + u.w * cv[3];
    }

    // ffn dot: 64 fp32 per lane, contiguous, 16x 16B loads
    float sf = 0.f;
    const float* wo = w_out + e * FFN_DIM + lane * 64;
    const float* hp = h + lane * 64;
    #pragma unroll
    for (int c = 0; c < 16; ++c) {
        f32x4 u = *(const f32x4*)(wo + c * 4);
        f32x4 hv = *(const f32x4*)(hp + c * 4);
        sf += u.x * hv.x + u.y * hv.y + u.z * hv.z + u.w * hv.w;
    }

    #pragma unroll
    for (int m = 32; m >= 1; m >>= 1) {
        sa += __shfl_xor(sa, m, 64);
        sf += __shfl_xor(sf, m, 64);
    }
    if (lane == 0) {
        attn_out[e] = sa;
        ffn_out[e] = sf;
    }
}

// --- Kernel C: fused double layernorm, one wave per token (row of 1024) ---
__global__ __launch_bounds__(256) void k_main(const float* __restrict__ x,
                                              const float* __restrict__ attn_out,
                                              const float* __restrict__ ffn_out,
                                              const float* __restrict__ g1,
                                              const float* __restrict__ b1,
                                              const float* __restrict__ g2,
                                              const float* __restrict__ b2,
                                              float* __restrict__ out) {
    int token = blockIdx.x * 4 + (threadIdx.x >> 6);
    int lane = threadIdx.x & 63;
    const int base = token * EMBED;

    // Each lane handles 16 elements: 4 chunks of float4, chunk c at c*256 + lane*4
    float y[16];
    float s = 0.f, s2 = 0.f;
    #pragma unroll
    for (int c = 0; c < 4; ++c) {
        int off = c * 256 + lane * 4;
        f32x4 u = *(const f32x4*)(x + base + off);
        f32x4 a = *(const f32x4*)(attn_out + off);
        #pragma unroll
        for (int k = 0; k < 4; ++k) {
            float v = u[k] + a[k];
            y[c * 4 + k] = v;
            s += v;
            s2 += v * v;
        }
    }
    #pragma unroll
    for (int m = 32; m >= 1; m >>= 1) {
        s += __shfl_xor(s, m, 64);
        s2 += __shfl_xor(s2, m, 64);
    }
    float m1 = s * (1.f / EMBED);
    float rs1 = rsqrtf(s2 * (1.f / EMBED) - m1 * m1 + EPS);

    float z[16];
    float t = 0.f, t2 = 0.f;
    #pragma unroll
    for (int c = 0; c < 4; ++c) {
        int off = c * 256 + lane * 4;
        f32x4 ug = *(const f32x4*)(g1 + off);
        f32x4 ub = *(const f32x4*)(b1 + off);
        f32x4 fo = *(const f32x4*)(ffn_out + off);
        #pragma unroll
        for (int k = 0; k < 4; ++k) {
            float x1 = ug[k] * (y[c * 4 + k] - m1) * rs1 + ub[k];
            float v = x1 + fo[k];
            z[c * 4 + k] = v;
            t += v;
            t2 += v * v;
        }
    }
    #pragma unroll
    for (int m = 32; m >= 1; m >>= 1) {
        t += __shfl_xor(t, m, 64);
        t2 += __shfl_xor(t2, m, 64);
    }
    float m2 = t * (1.f / EMBED);
    float rs2 = rsqrtf(t2 * (1.f / EMBED) - m2 * m2 + EPS);

    #pragma unroll
    for (int c = 0; c < 4; ++c) {
        int off = c * 256 + lane * 4;
        f32x4 ug = *(const f32x4*)(g2 + off);
        f32x4 ub = *(const f32x4*)(b2 + off);
        f32x4 o;
        #pragma unroll
        for (int k = 0; k < 4; ++k) {
            o[k] = ug[k] * (z[c * 4 + k] - m2) * rs2 + ub[k];
        }
        *(f32x4*)(out + base + off) = o;
    }
}

extern "C" void kernel_launch(void* const* d_in, const int* in_sizes, int n_in,
                              void* d_out, int out_size, void* d_ws, size_t ws_size,
                              hipStream_t stream) {
    // setup_inputs() order:
    // 0:x 1:wq 2:wk 3:wv 4:w_mix 5:attn_params 6:w1 7:w2 8:w_out 9:ffn_params
    // 10:ln1_g 11:ln1_b 12:ln2_g 13:ln2_b
    const float* x      = (const float*)d_in[0];
    const float* w_mix  = (const float*)d_in[4];
    const float* attn_p = (const float*)d_in[5];
    const float* w2     = (const float*)d_in[7];
    const float* w_out  = (const float*)d_in[8];
    const float* ffn_p  = (const float*)d_in[9];
    const float* ln1_g  = (const float*)d_in[10];
    const float* ln1_b  = (const float*)d_in[11];
    const float* ln2_g  = (const float*)d_in[12];
    const float* ln2_b  = (const float*)d_in[13];
    float* out = (float*)d_out;

    // workspace layout (fp32): [0,1024) attn_out | [1024,2048) ffn_out | [2048,6144) h
    float* ws_f     = (float*)d_ws;
    float* attn_out = ws_f;
    float* ffn_out  = ws_f + 1024;
    float* h        = ws_f + 2048;

    k_hidden<<<FFN_DIM / 256, 256, 0, stream>>>(w2, ffn_p, h);
    k_const<<<EMBED / 4, 256, 0, stream>>>(w_mix, attn_p, w_out, h, attn_out, ffn_out);
    k_main<<<TOKENS / 4, 256, 0, stream>>>(x, attn_out, ffn_out,
                                           ln1_g, ln1_b, ln2_g, ln2_b, out);
}